// Round 2
// baseline (44690.945 us; speedup 1.0000x reference)
//
#include <hip/hip_runtime.h>

#define EPSF 1e-5f

typedef unsigned short u16;
typedef unsigned int u32;

__device__ __forceinline__ u16 f2bf(float f) {
  u32 u = __float_as_uint(f);
  u += 0x7fffu + ((u >> 16) & 1u);   // RNE
  return (u16)(u >> 16);
}
__device__ __forceinline__ float bflo(u32 u) { return __uint_as_float(u << 16); }
__device__ __forceinline__ float bfhi(u32 u) { return __uint_as_float(u & 0xffff0000u); }
__device__ __forceinline__ float bf2f(u16 u) { return __uint_as_float(((u32)u) << 16); }

// One-time: convert weights to bf16, same row-major layout.
__global__ void prep_weights(const float* __restrict__ W1, const float* __restrict__ W2,
                             u16* __restrict__ W1b, u16* __restrict__ W2b) {
  int i = blockIdx.x * blockDim.x + threadIdx.x;
  if (i < 1024 * 512) W1b[i] = f2bf(W1[i]);
  if (i < 512 * 512)  W2b[i] = f2bf(W2[i]);
}

template<bool BF16W>
__global__ __launch_bounds__(1024)
void rnn_kernel(const float* __restrict__ xs, const float* __restrict__ h0,
                const float* __restrict__ gamma, const float* __restrict__ beta,
                const float* __restrict__ W1f, const u16* __restrict__ W1b,
                const float* __restrict__ lnh_w, const float* __restrict__ lnh_b,
                const float* __restrict__ W2f, const u16* __restrict__ W2b,
                const float* __restrict__ lnx_w, const float* __restrict__ lnx_b,
                float* __restrict__ out) {
  const int b = blockIdx.x;
  const int tid = threadIdx.x;
  const int N = 512, T = 1024;

  __shared__ __align__(16) float h_s[512];
  __shared__ __align__(16) float x_s[512];
  __shared__ float il_s[512];
  __shared__ float hg_s[512];
  __shared__ float p2[1024];
  __shared__ float red_s[16], red_q[16];
  __shared__ float stat[4];                       // mu1, rinv1, mu2, rinv2
  __shared__ __align__(16) u16   xs_t[3 * 512 * 16];   // 48 KB, bf16 xs tile
  __shared__ __align__(16) float out_t[512 * 16];      // 32 KB, out tile

  if (tid < N) h_s[tid] = h0[b * N + tid];

  // persistent per-thread params
  const float w1w = lnh_w[tid], w1b = lnh_b[tid];
  float g0 = 0, g1 = 0, g2 = 0, b0 = 0, b1 = 0, b2 = 0, w2w = 0, w2b = 0;
  if (tid < N) {
    g0 = gamma[0 * N + tid]; g1 = gamma[1 * N + tid]; g2 = gamma[2 * N + tid];
    b0 = beta[0 * N + tid];  b1 = beta[1 * N + tid];  b2 = beta[2 * N + tid];
    w2w = lnx_w[tid]; w2b = lnx_b[tid];
  }
  const float* xs_b = xs + (size_t)b * 3 * N * T;
  const int w = tid >> 6;
  __syncthreads();

  for (int t = 0; t < T; ++t) {
    // ---- stage 16 steps of xs into LDS (coalesced full-line reads, bf16) ----
    if ((t & 15) == 0) {
      for (int F = tid; F < 6144; F += 1024) {      // 6144 float4 chunks
        int pn = F >> 2;                            // p*512+n, 0..1535
        int q  = F & 3;                             // 4-step subgroup
        float4 v = *(const float4*)(xs_b + (size_t)pn * 1024 + t + q * 4);
        ushort4 u;
        u.x = f2bf(v.x); u.y = f2bf(v.y); u.z = f2bf(v.z); u.w = f2bf(v.w);
        *(ushort4*)(&xs_t[pn * 16 + q * 4]) = u;
      }
      __syncthreads();
    }
    const int tt = t & 15;

    // ---- in_layer (tid<512) from LDS xs tile ----
    if (tid < N) {
      float hv = h_s[tid];
      float s0 = 1.f / (1.f + __expf(-(g0 * hv + b0)));
      float s1 = 1.f / (1.f + __expf(-(g1 * hv + b1)));
      float s2 = 1.f / (1.f + __expf(-(g2 * hv + b2)));
      float x0 = bf2f(xs_t[(0 * 512 + tid) * 16 + tt]);
      float x1 = bf2f(xs_t[(1 * 512 + tid) * 16 + tt]);
      float x2 = bf2f(xs_t[(2 * 512 + tid) * 16 + tt]);
      il_s[tid] = fmaxf(s0 * x0 + s1 * x1 + s2 * x2, 0.f);
    }

    // ---- mm1: row-major weight row per thread, 16B vector loads ----
    float acc;
    {
      float a0 = 0.f, a1 = 0.f;
      if (BF16W) {
        const uint4* wp = (const uint4*)(W1b + (size_t)tid * 512);
        #pragma unroll 4
        for (int c = 0; c < 64; ++c) {
          uint4 wv = wp[c];
          float4 ha = *(const float4*)(h_s + c * 8);
          float4 hb = *(const float4*)(h_s + c * 8 + 4);
          a0 = fmaf(bflo(wv.x), ha.x, a0); a1 = fmaf(bfhi(wv.x), ha.y, a1);
          a0 = fmaf(bflo(wv.y), ha.z, a0); a1 = fmaf(bfhi(wv.y), ha.w, a1);
          a0 = fmaf(bflo(wv.z), hb.x, a0); a1 = fmaf(bfhi(wv.z), hb.y, a1);
          a0 = fmaf(bflo(wv.w), hb.z, a0); a1 = fmaf(bfhi(wv.w), hb.w, a1);
        }
      } else {
        const float4* wp = (const float4*)(W1f + (size_t)tid * 512);
        #pragma unroll 4
        for (int c = 0; c < 128; ++c) {
          float4 wv = wp[c];
          float4 hv = *(const float4*)(h_s + c * 4);
          a0 = fmaf(wv.x, hv.x, a0); a1 = fmaf(wv.y, hv.y, a1);
          a0 = fmaf(wv.z, hv.z, a0); a1 = fmaf(wv.w, hv.w, a1);
        }
      }
      acc = a0 + a1;
    }

    // ---- LN1 stats over 1024 ----
    {
      float s = acc, q = acc * acc;
      #pragma unroll
      for (int off = 32; off > 0; off >>= 1) {
        s += __shfl_down(s, off); q += __shfl_down(q, off);
      }
      if ((tid & 63) == 0) { red_s[w] = s; red_q[w] = q; }
    }
    __syncthreads();
    if (tid == 0) {
      float ss = 0.f, qq = 0.f;
      #pragma unroll
      for (int i = 0; i < 16; ++i) { ss += red_s[i]; qq += red_q[i]; }
      float mu = ss * (1.f / 1024.f);
      float var = qq * (1.f / 1024.f) - mu * mu;
      stat[0] = mu; stat[1] = rsqrtf(var + EPSF);
    }
    __syncthreads();

    // ---- LN1 apply; build x and h_g ----
    {
      float hh = (acc - stat[0]) * stat[1] * w1w + w1b;
      if (tid < N) x_s[tid] = fmaxf(il_s[tid] + hh, 0.f);
      else         hg_s[tid - N] = hh;
    }
    __syncthreads();

    // ---- mm2: k-split across thread halves ----
    {
      const int n = tid & 511;
      const int half = tid >> 9;
      float a0 = 0.f, a1 = 0.f;
      if (BF16W) {
        const uint4* wp = (const uint4*)(W2b + (size_t)n * 512 + half * 256);
        const float* xh = x_s + half * 256;
        #pragma unroll 4
        for (int c = 0; c < 32; ++c) {
          uint4 wv = wp[c];
          float4 ha = *(const float4*)(xh + c * 8);
          float4 hb = *(const float4*)(xh + c * 8 + 4);
          a0 = fmaf(bflo(wv.x), ha.x, a0); a1 = fmaf(bfhi(wv.x), ha.y, a1);
          a0 = fmaf(bflo(wv.y), ha.z, a0); a1 = fmaf(bfhi(wv.y), ha.w, a1);
          a0 = fmaf(bflo(wv.z), hb.x, a0); a1 = fmaf(bfhi(wv.z), hb.y, a1);
          a0 = fmaf(bflo(wv.w), hb.z, a0); a1 = fmaf(bfhi(wv.w), hb.w, a1);
        }
      } else {
        const float4* wp = (const float4*)(W2f + (size_t)n * 512 + half * 256);
        const float* xh = x_s + half * 256;
        #pragma unroll 4
        for (int c = 0; c < 64; ++c) {
          float4 wv = wp[c];
          float4 hv = *(const float4*)(xh + c * 4);
          a0 = fmaf(wv.x, hv.x, a0); a1 = fmaf(wv.y, hv.y, a1);
          a0 = fmaf(wv.z, hv.z, a0); a1 = fmaf(wv.w, hv.w, a1);
        }
      }
      p2[tid] = a0 + a1;
    }
    __syncthreads();

    // ---- combine halves + LN2 stats over 512 ----
    float accf = 0.f;
    {
      float s = 0.f, q = 0.f;
      if (tid < N) {
        accf = p2[tid] + p2[tid + 512];
        s = accf; q = accf * accf;
      }
      #pragma unroll
      for (int off = 32; off > 0; off >>= 1) {
        s += __shfl_down(s, off); q += __shfl_down(q, off);
      }
      if ((tid & 63) == 0) { red_s[w] = s; red_q[w] = q; }
    }
    __syncthreads();
    if (tid == 0) {
      float ss = 0.f, qq = 0.f;
      #pragma unroll
      for (int i = 0; i < 16; ++i) { ss += red_s[i]; qq += red_q[i]; }
      float mu = ss * (1.f / 512.f);
      float var = qq * (1.f / 512.f) - mu * mu;
      stat[2] = mu; stat[3] = rsqrtf(var + EPSF);
    }
    __syncthreads();

    // ---- gate + state update into LDS out tile ----
    if (tid < N) {
      float y = (accf - stat[2]) * stat[3] * w2w + w2b;
      float gg = 1.f / (1.f + __expf(-(y + hg_s[tid])));
      float hn = (1.f - gg) * h_s[tid] + gg * x_s[tid];
      out_t[tid * 16 + tt] = hn;
      h_s[tid] = hn;
    }
    __syncthreads();

    // ---- flush out tile every 16 steps (full-line coalesced stores) ----
    if ((t & 15) == 15) {
      const int n = tid >> 1;
      const int i0 = (tid & 1) * 8;
      float4 va = *(const float4*)(out_t + n * 16 + i0);
      float4 vb = *(const float4*)(out_t + n * 16 + i0 + 4);
      float* op = out + ((size_t)b * N + n) * T + (t - 15) + i0;
      *(float4*)op = va;
      *(float4*)(op + 4) = vb;
    }
  }
}

extern "C" void kernel_launch(void* const* d_in, const int* in_sizes, int n_in,
                              void* d_out, int out_size, void* d_ws, size_t ws_size,
                              hipStream_t stream) {
  const float* xs    = (const float*)d_in[0];
  const float* h0    = (const float*)d_in[1];
  const float* gamma = (const float*)d_in[2];
  const float* beta  = (const float*)d_in[3];
  const float* W1    = (const float*)d_in[4];
  const float* lnh_w = (const float*)d_in[5];
  const float* lnh_b = (const float*)d_in[6];
  const float* W2    = (const float*)d_in[7];
  const float* lnx_w = (const float*)d_in[8];
  const float* lnx_b = (const float*)d_in[9];
  float* out = (float*)d_out;

  const size_t need = (size_t)(1024 * 512 + 512 * 512) * sizeof(u16);
  if (ws_size >= need) {
    u16* W1b = (u16*)d_ws;
    u16* W2b = W1b + 1024 * 512;
    prep_weights<<<(1024 * 512 + 255) / 256, 256, 0, stream>>>(W1, W2, W1b, W2b);
    rnn_kernel<true><<<64, 1024, 0, stream>>>(xs, h0, gamma, beta, W1, W1b,
                                              lnh_w, lnh_b, W2, W2b, lnx_w, lnx_b, out);
  } else {
    rnn_kernel<false><<<64, 1024, 0, stream>>>(xs, h0, gamma, beta, W1, nullptr,
                                               lnh_w, lnh_b, W2, nullptr, lnx_w, lnx_b, out);
  }
}

// Round 3
// 17780.157 us; speedup vs baseline: 2.5135x; 2.5135x over previous
//
#include <hip/hip_runtime.h>

#define EPSF 1e-5f

typedef unsigned short u16;
typedef unsigned int u32;

__device__ __forceinline__ u16 f2bf(float f) {
  u32 u = __float_as_uint(f);
  u += 0x7fffu + ((u >> 16) & 1u);   // RNE
  return (u16)(u >> 16);
}
__device__ __forceinline__ u32 packbf(float lo, float hi) {
  return (u32)f2bf(lo) | ((u32)f2bf(hi) << 16);
}

#if __has_builtin(__builtin_amdgcn_fdot2_f32_bf16)
typedef __attribute__((ext_vector_type(2))) __bf16 bf16x2;
__device__ __forceinline__ float dot2bf(u32 w, u32 h, float acc) {
  union { u32 u; bf16x2 v; } a, b; a.u = w; b.u = h;
  return __builtin_amdgcn_fdot2_f32_bf16(a.v, b.v, acc, false);
}
#else
__device__ __forceinline__ float dot2bf(u32 w, u32 h, float acc) {
  float r = fmaf(__uint_as_float(w << 16), __uint_as_float(h << 16), acc);
  return fmaf(__uint_as_float(w & 0xffff0000u), __uint_as_float(h & 0xffff0000u), r);
}
#endif

// Pack weights for lane-coalesced 16B loads:
// W1p: u16 index (kk*1024 + j)*8 + r  holds bf16(W1[j][kk*8+r]),  kk=0..63, j=0..1023
// W2p: u16 index (kk*512  + n)*8 + r  holds bf16(W2[n][kk*8+r]),  kk=0..63, n=0..511
__global__ void prep_weights(const float* __restrict__ W1, const float* __restrict__ W2,
                             u16* __restrict__ W1p, u16* __restrict__ W2p) {
  int i = blockIdx.x * blockDim.x + threadIdx.x;
  if (i < 1024 * 64) {
    int j = i >> 6, kk = i & 63;
    const float* src = W1 + (size_t)j * 512 + kk * 8;
    u16* dst = W1p + ((size_t)(kk * 1024 + j)) * 8;
    #pragma unroll
    for (int r = 0; r < 8; ++r) dst[r] = f2bf(src[r]);
  }
  if (i < 512 * 64) {
    int n = i >> 6, kk = i & 63;
    const float* src = W2 + (size_t)n * 512 + kk * 8;
    u16* dst = W2p + ((size_t)(kk * 512 + n)) * 8;
    #pragma unroll
    for (int r = 0; r < 8; ++r) dst[r] = f2bf(src[r]);
  }
}

__global__ __launch_bounds__(1024)
void rnn_kernel(const float* __restrict__ xs, const float* __restrict__ h0,
                const float* __restrict__ gamma, const float* __restrict__ beta,
                const u16* __restrict__ W1p,
                const float* __restrict__ lnh_w, const float* __restrict__ lnh_b,
                const u16* __restrict__ W2p,
                const float* __restrict__ lnx_w, const float* __restrict__ lnx_b,
                float* __restrict__ out) {
  const int b = blockIdx.x;
  const int tid = threadIdx.x;
  const int N = 512;

  __shared__ float hg_s[512];
  __shared__ float p2[1024];
  __shared__ u32 hb2[256];
  __shared__ u32 xb2[256];
  __shared__ float red_s[16], red_q[16];
  __shared__ float stat[4];
  __shared__ __align__(16) float out_t[32][512];   // 64 KB, t-major (conflict-free)
  __shared__ float pad_[2560];                     // pin 1 block/CU (total ~82 KB)

  const int w = tid >> 6;

  // persistent per-thread params
  const float w1w = lnh_w[tid], w1b = lnh_b[tid];
  float g0 = 0, g1 = 0, g2 = 0, b0 = 0, b1 = 0, b2 = 0, w2w = 0, w2b = 0;
  float hv = 0.f, xv = 0.f, il = 0.f;
  if (tid < N) {
    g0 = gamma[0 * N + tid]; g1 = gamma[1 * N + tid]; g2 = gamma[2 * N + tid];
    b0 = beta[0 * N + tid];  b1 = beta[1 * N + tid];  b2 = beta[2 * N + tid];
    w2w = lnx_w[tid]; w2b = lnx_b[tid];
    hv = h0[(size_t)b * N + tid];
    float hnb = __shfl_down(hv, 1);
    if (!(tid & 1)) hb2[tid >> 1] = packbf(hv, hnb);
  }
  if (gamma[0] > 1e30f) pad_[0] = 1.f;   // keep pad_ alive
  const float* xs_b = xs + (size_t)b * 3 * N * 1024;
  __syncthreads();

  for (int t0 = 0; t0 < 1024; t0 += 4) {
    float4 xr0, xr1, xr2;
    if (tid < N) {
      xr0 = *(const float4*)(xs_b + (size_t)(0 * N + tid) * 1024 + t0);
      xr1 = *(const float4*)(xs_b + (size_t)(1 * N + tid) * 1024 + t0);
      xr2 = *(const float4*)(xs_b + (size_t)(2 * N + tid) * 1024 + t0);
    }
    #pragma unroll
    for (int q = 0; q < 4; ++q) {
      const int t = t0 + q;
      const int tt = t & 31;

      // ---- in_layer (registers only) ----
      if (tid < N) {
        float s0 = 1.f / (1.f + __expf(-(g0 * hv + b0)));
        float s1 = 1.f / (1.f + __expf(-(g1 * hv + b1)));
        float s2 = 1.f / (1.f + __expf(-(g2 * hv + b2)));
        float x0 = (q == 0) ? xr0.x : (q == 1) ? xr0.y : (q == 2) ? xr0.z : xr0.w;
        float x1 = (q == 0) ? xr1.x : (q == 1) ? xr1.y : (q == 2) ? xr1.z : xr1.w;
        float x2 = (q == 0) ? xr2.x : (q == 1) ? xr2.y : (q == 2) ? xr2.z : xr2.w;
        il = fmaxf(s0 * x0 + s1 * x1 + s2 * x2, 0.f);
      }

      // ---- mm1: coalesced dwordx4 weight loads + dot2 ----
      float acc;
      {
        const u32* wp = (const u32*)W1p + (size_t)tid * 4;
        float a0 = 0.f, a1 = 0.f;
        #pragma unroll 8
        for (int kk = 0; kk < 64; ++kk) {
          uint4 wv = *(const uint4*)(wp + (size_t)kk * 4096);
          uint4 hv4 = *(const uint4*)(hb2 + kk * 4);
          a0 = dot2bf(wv.x, hv4.x, a0); a1 = dot2bf(wv.y, hv4.y, a1);
          a0 = dot2bf(wv.z, hv4.z, a0); a1 = dot2bf(wv.w, hv4.w, a1);
        }
        acc = a0 + a1;
      }

      // ---- LN1 stats over 1024 ----
      {
        float s = acc, qq = acc * acc;
        #pragma unroll
        for (int off = 32; off > 0; off >>= 1) {
          s += __shfl_down(s, off); qq += __shfl_down(qq, off);
        }
        if ((tid & 63) == 0) { red_s[w] = s; red_q[w] = qq; }
      }
      __syncthreads();
      if (tid == 0) {
        float ss = 0.f, qq = 0.f;
        #pragma unroll
        for (int i = 0; i < 16; ++i) { ss += red_s[i]; qq += red_q[i]; }
        float mu = ss * (1.f / 1024.f);
        float var = qq * (1.f / 1024.f) - mu * mu;
        stat[0] = mu; stat[1] = rsqrtf(var + EPSF);
      }
      __syncthreads();

      // ---- LN1 apply: x (regs + packed LDS) and h_g ----
      {
        float hh = (acc - stat[0]) * stat[1] * w1w + w1b;
        if (tid < N) {
          xv = fmaxf(il + hh, 0.f);
          float xnb = __shfl_down(xv, 1);
          if (!(tid & 1)) xb2[tid >> 1] = packbf(xv, xnb);
        } else {
          hg_s[tid - N] = hh;
        }
      }
      __syncthreads();

      // ---- mm2: k-split halves, coalesced + dot2 ----
      {
        const int n = tid & 511;
        const int half = tid >> 9;
        const u32* wp = (const u32*)W2p + (size_t)n * 4 + (size_t)(half * 32) * 2048;
        const u32* xp = xb2 + half * 128;
        float c0 = 0.f, c1 = 0.f;
        #pragma unroll 8
        for (int kk = 0; kk < 32; ++kk) {
          uint4 wv = *(const uint4*)(wp + (size_t)kk * 2048);
          uint4 xv4 = *(const uint4*)(xp + kk * 4);
          c0 = dot2bf(wv.x, xv4.x, c0); c1 = dot2bf(wv.y, xv4.y, c1);
          c0 = dot2bf(wv.z, xv4.z, c0); c1 = dot2bf(wv.w, xv4.w, c1);
        }
        p2[tid] = c0 + c1;
      }
      __syncthreads();

      // ---- LN2 stats over 512 ----
      float accf = 0.f;
      {
        float s = 0.f, qq = 0.f;
        if (tid < N) {
          accf = p2[tid] + p2[tid + 512];
          s = accf; qq = accf * accf;
        }
        #pragma unroll
        for (int off = 32; off > 0; off >>= 1) {
          s += __shfl_down(s, off); qq += __shfl_down(qq, off);
        }
        if ((tid & 63) == 0) { red_s[w] = s; red_q[w] = qq; }
      }
      __syncthreads();
      if (tid == 0) {
        float ss = 0.f, qq = 0.f;
        #pragma unroll
        for (int i = 0; i < 16; ++i) { ss += red_s[i]; qq += red_q[i]; }
        float mu = ss * (1.f / 512.f);
        float var = qq * (1.f / 512.f) - mu * mu;
        stat[2] = mu; stat[3] = rsqrtf(var + EPSF);
      }
      __syncthreads();

      // ---- gate + state update (h stays in registers) ----
      if (tid < N) {
        float y = (accf - stat[2]) * stat[3] * w2w + w2b;
        float gg = 1.f / (1.f + __expf(-(y + hg_s[tid])));
        float hn = hv + gg * (xv - hv);
        out_t[tt][tid] = hn;
        hv = hn;
        float hnb = __shfl_down(hn, 1);
        if (!(tid & 1)) hb2[tid >> 1] = packbf(hn, hnb);
      }
      __syncthreads();

      // ---- flush out tile every 32 steps (full-line coalesced stores) ----
      if (tt == 31) {
        const int n = tid >> 1;
        const int seg = tid & 1;
        float* op = out + ((size_t)b * N + n) * 1024 + (t - 31) + seg * 16;
        #pragma unroll
        for (int i = 0; i < 4; ++i) {
          float4 v;
          v.x = out_t[seg * 16 + i * 4 + 0][n];
          v.y = out_t[seg * 16 + i * 4 + 1][n];
          v.z = out_t[seg * 16 + i * 4 + 2][n];
          v.w = out_t[seg * 16 + i * 4 + 3][n];
          *(float4*)(op + i * 4) = v;
        }
      }
    }
  }
}

extern "C" void kernel_launch(void* const* d_in, const int* in_sizes, int n_in,
                              void* d_out, int out_size, void* d_ws, size_t ws_size,
                              hipStream_t stream) {
  const float* xs    = (const float*)d_in[0];
  const float* h0    = (const float*)d_in[1];
  const float* gamma = (const float*)d_in[2];
  const float* beta  = (const float*)d_in[3];
  const float* W1    = (const float*)d_in[4];
  const float* lnh_w = (const float*)d_in[5];
  const float* lnh_b = (const float*)d_in[6];
  const float* W2    = (const float*)d_in[7];
  const float* lnx_w = (const float*)d_in[8];
  const float* lnx_b = (const float*)d_in[9];
  float* out = (float*)d_out;

  u16* W1p = (u16*)d_ws;                    // 1 MB
  u16* W2p = W1p + (size_t)1024 * 512;      // 0.5 MB

  prep_weights<<<(65536 + 255) / 256, 256, 0, stream>>>(W1, W2, W1p, W2p);
  rnn_kernel<<<64, 1024, 0, stream>>>(xs, h0, gamma, beta, W1p,
                                      lnh_w, lnh_b, W2p, lnx_w, lnx_b, out);
}